// Round 2
// baseline (99.171 us; speedup 1.0000x reference)
//
#include <hip/hip_runtime.h>
#include <hip/hip_bf16.h>
#include <stdint.h>

#define S_SCALE 30.0f
#define N_ROWS 8192
#define D_DIM 256
#define C_CLS 10000
#define C_PAD 10112   /* 79 * 128 */
#define NCB 79
#define PSTRIDE 80

typedef __attribute__((ext_vector_type(8))) short short8;
typedef __attribute__((ext_vector_type(16))) float f32x16;
typedef __attribute__((ext_vector_type(4))) unsigned short us4;

static __device__ __forceinline__ unsigned short f2bf(float f) {
  union { float f; unsigned u; } a; a.f = f;
  unsigned r = a.u + 0x7fffu + ((a.u >> 16) & 1u);
  return (unsigned short)(r >> 16);
}

static __device__ __forceinline__ void gl16(const void* g, void* l) {
  __builtin_amdgcn_global_load_lds(
      (const __attribute__((address_space(1))) void*)g,
      (__attribute__((address_space(3))) void*)l, 16, 0, 0);
}

// ------- fused: row L2-normalize -> bf16, exact fp32 target logit -------
__global__ __launch_bounds__(256) void k_normtgt(const float* __restrict__ x,
                                                 const float* __restrict__ W,
                                                 const int* __restrict__ target,
                                                 unsigned short* __restrict__ xnb,
                                                 float* __restrict__ tgt) {
  int row = blockIdx.x * 4 + (threadIdx.x >> 6);
  int l = threadIdx.x & 63;
  const float4 v = *(const float4*)(x + (size_t)row * D_DIM + l * 4);
  float ss = v.x * v.x + v.y * v.y + v.z * v.z + v.w * v.w;
#pragma unroll
  for (int m = 1; m < 64; m <<= 1) ss += __shfl_xor(ss, m, 64);
  float rn = 1.0f / sqrtf(ss);
  us4 o;
  o.x = f2bf(v.x * rn); o.y = f2bf(v.y * rn);
  o.z = f2bf(v.z * rn); o.w = f2bf(v.w * rn);
  *(us4*)(xnb + (size_t)row * D_DIM + l * 4) = o;
  // exact fp32 target-class logit
  int tc = target[row];
  const float4 b = *(const float4*)(W + (size_t)tc * D_DIM + l * 4);
  float s = v.x * b.x + v.y * b.y + v.z * b.z + v.w * b.w;
#pragma unroll
  for (int m = 1; m < 64; m <<= 1) s += __shfl_xor(s, m, 64);
  if (l == 0) tgt[row] = s * rn;
}

// ---------------- W fp32 -> bf16, zero-pad rows to C_PAD ----------------
__global__ __launch_bounds__(256) void k_convw(const float* __restrict__ W,
                                               unsigned short* __restrict__ Wb) {
  int idx = blockIdx.x * 256 + threadIdx.x;   // 8 elems per thread
  size_t base = (size_t)idx * 8;
  int row = (int)(base >> 8);
  us4 o0 = {0, 0, 0, 0}, o1 = {0, 0, 0, 0};
  if (row < C_CLS) {
    const float4 a = *(const float4*)(W + base);
    const float4 b = *(const float4*)(W + base + 4);
    o0.x = f2bf(a.x); o0.y = f2bf(a.y); o0.z = f2bf(a.z); o0.w = f2bf(a.w);
    o1.x = f2bf(b.x); o1.y = f2bf(b.y); o1.z = f2bf(b.z); o1.w = f2bf(b.w);
  }
  *(us4*)(Wb + base) = o0;
  *(us4*)(Wb + base + 4) = o1;
}

// ---------------- fused bf16 GEMM + exp-sum epilogue ----------------
// 128x128 tile, BK=32, 32x32x16 MFMA, 4 waves (2x2), each wave 64x64 = 2x2 frags.
// XCD-banded block swizzle: each XCD owns a contiguous column band, rows inner.
// LDS slot-swizzle: lds[row][u] = global[row][u ^ ((row>>1)&3)] (16B slots),
// written via pre-swizzled global source (global_load_lds dest stays linear),
// read with the same XOR -> balanced 8 lanes per 16B bank-slot group.
__global__ __launch_bounds__(256, 4) void k_gemm(const unsigned short* __restrict__ xnb,
                                                 const unsigned short* __restrict__ Wb,
                                                 float* __restrict__ partials) {
  __shared__ __align__(16) char ldsA[2][8192];
  __shared__ __align__(16) char ldsB[2][8192];
  int id = blockIdx.x;
  int vid = (id & 7) * 632 + (id >> 3);   // 5056 = 8 * 632, bijective
  int bc = vid >> 6;                      // 0..78  (column panel, per-XCD band)
  int br = vid & 63;                      // 0..63  (row panel, inner loop)
  int t = threadIdx.x;
  int w = t >> 6, l = t & 63;
  int wr = w >> 1, wc = w & 1;
  const char* Ag = (const char*)xnb + (size_t)br * 128 * 512;  // 512 B/row
  const char* Bg = (const char*)Wb + (size_t)bc * 128 * 512;

  f32x16 acc[2][2];
#pragma unroll
  for (int m = 0; m < 2; m++)
#pragma unroll
    for (int n = 0; n < 2; n++)
#pragma unroll
      for (int j = 0; j < 16; j++) acc[m][n][j] = 0.f;

  auto stage = [&](int buf, int kt) {
#pragma unroll
    for (int c = 0; c < 2; ++c) {
      int p = c * 4096 + t * 16;          // linear dest byte in 8 KB chunk
      int row = p >> 6;                   // 64 B per row (BK=32 bf16)
      int u = (p >> 4) & 3;               // 16B slot in row
      int su = u ^ ((row >> 1) & 3);      // pre-swizzled source slot
      size_t go = (size_t)row * 512 + (size_t)kt * 64 + (size_t)(su << 4);
      int lo = c * 4096 + w * 1024;       // wave-uniform LDS base (+lane*16)
      gl16(Ag + go, &ldsA[buf][lo]);
      gl16(Bg + go, &ldsB[buf][lo]);
    }
  };

  int lr = l & 31, hi = l >> 5;
  int sw = (lr >> 1) & 3;

  auto compute = [&](int buf) {
#pragma unroll
    for (int kc = 0; kc < 2; ++kc) {
      int so = (((kc << 1) + hi) ^ sw) << 4;
      short8 a0 = *(const short8*)(ldsA[buf] + (wr * 64 + lr) * 64 + so);
      short8 a1 = *(const short8*)(ldsA[buf] + (wr * 64 + 32 + lr) * 64 + so);
      short8 b0 = *(const short8*)(ldsB[buf] + (wc * 64 + lr) * 64 + so);
      short8 b1 = *(const short8*)(ldsB[buf] + (wc * 64 + 32 + lr) * 64 + so);
      acc[0][0] = __builtin_amdgcn_mfma_f32_32x32x16_bf16(a0, b0, acc[0][0], 0, 0, 0);
      acc[0][1] = __builtin_amdgcn_mfma_f32_32x32x16_bf16(a0, b1, acc[0][1], 0, 0, 0);
      acc[1][0] = __builtin_amdgcn_mfma_f32_32x32x16_bf16(a1, b0, acc[1][0], 0, 0, 0);
      acc[1][1] = __builtin_amdgcn_mfma_f32_32x32x16_bf16(a1, b1, acc[1][1], 0, 0, 0);
    }
  };

  stage(0, 0);
  __syncthreads();
#pragma unroll
  for (int kt = 0; kt < 8; ++kt) {
    int cur = kt & 1;
    if (kt < 7) stage(cur ^ 1, kt + 1);
    compute(cur);
    __syncthreads();
  }

  // Epilogue: exp(S*logit) masked to col<C, per-A-row sums.
  // C/D 32x32 layout: col = lane&31, row = (reg&3) + 8*(reg>>2) + 4*(lane>>5).
  float rs[2][16];
#pragma unroll
  for (int m = 0; m < 2; m++)
#pragma unroll
    for (int j = 0; j < 16; j++) rs[m][j] = 0.f;
#pragma unroll
  for (int n = 0; n < 2; n++) {
    int col = bc * 128 + wc * 64 + n * 32 + lr;
    bool ok = (col < C_CLS);
#pragma unroll
    for (int m = 0; m < 2; m++)
#pragma unroll
      for (int j = 0; j < 16; j++)
        rs[m][j] += ok ? __expf(S_SCALE * acc[m][n][j]) : 0.f;
  }
#pragma unroll
  for (int mask = 1; mask <= 16; mask <<= 1)
#pragma unroll
    for (int m = 0; m < 2; m++)
#pragma unroll
      for (int j = 0; j < 16; j++) rs[m][j] += __shfl_xor(rs[m][j], mask, 64);

  float* rowsum = (float*)&ldsA[0][0];  // 256 floats
  if (lr == 0) {
#pragma unroll
    for (int m = 0; m < 2; m++)
#pragma unroll
      for (int j = 0; j < 16; j++) {
        int row = wr * 64 + m * 32 + (j & 3) + 8 * (j >> 2) + 4 * hi;
        rowsum[wc * 128 + row] = rs[m][j];
      }
  }
  __syncthreads();
  if (t < 128)
    partials[(size_t)(br * 128 + t) * PSTRIDE + bc] = rowsum[t] + rowsum[128 + t];
}

// ---------------- per-row loss + block partial sums ----------------
__global__ __launch_bounds__(256) void k_loss1(const float* __restrict__ partials,
                                               const float* __restrict__ tgt,
                                               float* __restrict__ bsum) {
  __shared__ float wsum[4];
  int i = blockIdx.x * 256 + threadIdx.x;
  const float* p = partials + (size_t)i * PSTRIDE;
  float s = 0.f;
#pragma unroll
  for (int j = 0; j < NCB; ++j) s += p[j];
  float tl = tgt[i];
  float tcv = fminf(fmaxf(tl, -1.0f + 1e-7f), 1.0f - 1e-7f);
  const float cm = 0.95533648912560601964f;   // cos(0.3)
  const float sm = 0.29552020666133957510f;   // sin(0.3)
  // s*cos(acos(t)+m) = s*(t*cos m - sqrt(1-t^2)*sin m)
  float num = S_SCALE * (tcv * cm - sqrtf(fmaxf(1.0f - tcv * tcv, 0.f)) * sm);
  float sum_excl = s - __expf(S_SCALE * tl);
  float denom = __expf(num) + sum_excl;
  float L = num - __logf(denom);
#pragma unroll
  for (int m = 1; m < 64; m <<= 1) L += __shfl_xor(L, m, 64);
  int l = threadIdx.x & 63, w = threadIdx.x >> 6;
  if (l == 0) wsum[w] = L;
  __syncthreads();
  if (threadIdx.x == 0) bsum[blockIdx.x] = wsum[0] + wsum[1] + wsum[2] + wsum[3];
}

__global__ void k_loss2(const float* __restrict__ bsum, float* __restrict__ out) {
  float s = 0.f;
  for (int i = 0; i < 32; ++i) s += bsum[i];
  out[0] = -s / (float)N_ROWS;
}

// ---------------- launch ----------------
extern "C" void kernel_launch(void* const* d_in, const int* in_sizes, int n_in,
                              void* d_out, int out_size, void* d_ws, size_t ws_size,
                              hipStream_t stream) {
  const float* x = (const float*)d_in[0];
  const float* W = (const float*)d_in[1];
  const int* target = (const int*)d_in[2];
  float* out = (float*)d_out;
  char* ws = (char*)d_ws;

  unsigned short* xnb = (unsigned short*)(ws);              // 8192*256*2   = 4,194,304
  unsigned short* Wb = (unsigned short*)(ws + 4194304);     // 10112*256*2  = 5,177,344
  float* tgt = (float*)(ws + 9404416);                      // 8192*4
  float* partials = (float*)(ws + 9437184);                 // 8192*80*4    = 2,621,440
  float* bsum = (float*)(ws + 12058624);                    // 32*4

  k_normtgt<<<2048, 256, 0, stream>>>(x, W, target, xnb, tgt);
  k_convw<<<1264, 256, 0, stream>>>(W, Wb);
  k_gemm<<<5056, 256, 0, stream>>>(xnb, Wb, partials);
  k_loss1<<<32, 256, 0, stream>>>(partials, tgt, bsum);
  k_loss2<<<1, 1, 0, stream>>>(bsum, out);
}

// Round 3
// 82.000 us; speedup vs baseline: 1.2094x; 1.2094x over previous
//
#include <hip/hip_runtime.h>
#include <hip/hip_bf16.h>
#include <stdint.h>

#define S_SCALE 30.0f
#define N_ROWS 8192
#define D_DIM 256
#define C_CLS 10000
#define C_PAD 10240   /* 40 * 256 */
#define NCB 40
#define PSTRIDE 40

typedef __attribute__((ext_vector_type(8))) short short8;
typedef __attribute__((ext_vector_type(4))) float f32x4;
typedef __attribute__((ext_vector_type(4))) unsigned short us4;

static __device__ __forceinline__ unsigned short f2bf(float f) {
  union { float f; unsigned u; } a; a.f = f;
  unsigned r = a.u + 0x7fffu + ((a.u >> 16) & 1u);
  return (unsigned short)(r >> 16);
}

static __device__ __forceinline__ void gl16(const void* g, void* l) {
  __builtin_amdgcn_global_load_lds(
      (const __attribute__((address_space(1))) void*)g,
      (__attribute__((address_space(3))) void*)l, 16, 0, 0);
}

// ------- fused: row L2-normalize -> bf16, exact fp32 target logit -------
__global__ __launch_bounds__(256) void k_normtgt(const float* __restrict__ x,
                                                 const float* __restrict__ W,
                                                 const int* __restrict__ target,
                                                 unsigned short* __restrict__ xnb,
                                                 float* __restrict__ tgt) {
  int row = blockIdx.x * 4 + (threadIdx.x >> 6);
  int l = threadIdx.x & 63;
  const float4 v = *(const float4*)(x + (size_t)row * D_DIM + l * 4);
  float ss = v.x * v.x + v.y * v.y + v.z * v.z + v.w * v.w;
#pragma unroll
  for (int m = 1; m < 64; m <<= 1) ss += __shfl_xor(ss, m, 64);
  float rn = 1.0f / sqrtf(ss);
  us4 o;
  o.x = f2bf(v.x * rn); o.y = f2bf(v.y * rn);
  o.z = f2bf(v.z * rn); o.w = f2bf(v.w * rn);
  *(us4*)(xnb + (size_t)row * D_DIM + l * 4) = o;
  int tc = target[row];
  const float4 b = *(const float4*)(W + (size_t)tc * D_DIM + l * 4);
  float s = v.x * b.x + v.y * b.y + v.z * b.z + v.w * b.w;
#pragma unroll
  for (int m = 1; m < 64; m <<= 1) s += __shfl_xor(s, m, 64);
  if (l == 0) tgt[row] = s * rn;
}

// ---------------- W fp32 -> bf16, zero-pad rows to C_PAD ----------------
__global__ __launch_bounds__(256) void k_convw(const float* __restrict__ W,
                                               unsigned short* __restrict__ Wb) {
  int idx = blockIdx.x * 256 + threadIdx.x;   // 8 elems per thread
  size_t base = (size_t)idx * 8;
  int row = (int)(base >> 8);
  us4 o0 = {0, 0, 0, 0}, o1 = {0, 0, 0, 0};
  if (row < C_CLS) {
    const float4 a = *(const float4*)(W + base);
    const float4 b = *(const float4*)(W + base + 4);
    o0.x = f2bf(a.x); o0.y = f2bf(a.y); o0.z = f2bf(a.z); o0.w = f2bf(a.w);
    o1.x = f2bf(b.x); o1.y = f2bf(b.y); o1.z = f2bf(b.z); o1.w = f2bf(b.w);
  }
  *(us4*)(Wb + base) = o0;
  *(us4*)(Wb + base + 4) = o1;
}

// ------------- fused bf16 GEMM (256x256, 8-phase) + exp-sum epilogue -------------
// BM=BN=256, BK=64, 8 waves (2Mx4N), wave tile 128x64 = 8x4 frags of 16x16x32.
// 4 phases per K-tile; counted staging: next tile's 8 loads issued in phases 0-1,
// boundary vmcnt(0) lands ~3 phases later (fully latency-covered).
// T2 swizzle: LDS slot ^= row&7 (write via pre-swizzled global source, rule #21).
// T1: 2D XCD chunks (16 br x 10 bc) -> per-XCD working set 3.25 MB (L2-fit).
__global__ __launch_bounds__(512, 2) void k_gemm(const unsigned short* __restrict__ xnb,
                                                 const unsigned short* __restrict__ Wb,
                                                 float* __restrict__ partials) {
  __shared__ __align__(16) char ldsA[2][32768];
  __shared__ __align__(16) char ldsB[2][32768];
  int id = blockIdx.x;                 // 1280 = 8 XCD * 160
  int x8 = id & 7, u = id >> 3;        // u: 0..159
  int br = (x8 >> 2) * 16 + (u & 15);  // 0..31
  int bc = (x8 & 3) * 10 + (u >> 4);   // 0..39
  int t = threadIdx.x;
  int w = t >> 6, l = t & 63;
  int wr = w >> 2, wc = w & 3;         // 2M x 4N waves
  int lr = l & 15, lk = l >> 4;
  const char* Ag = (const char*)xnb + (size_t)br * 256 * 512;  // 512 B/row
  const char* Bg = (const char*)Wb + (size_t)bc * 256 * 512;

  f32x4 acc[8][4];
#pragma unroll
  for (int m = 0; m < 8; m++)
#pragma unroll
    for (int n = 0; n < 4; n++) acc[m][n] = (f32x4){0.f, 0.f, 0.f, 0.f};

  // stage half-set h (A-half h + B-half h) of K-tile kt into buffer buf
  auto stageHalf = [&](char* bufA, char* bufB, int kt, int h) {
#pragma unroll
    for (int i = 0; i < 2; ++i) {
      int p = h * 16384 + i * 8192 + t * 16;   // linear dest byte
      int row = p >> 7;                        // 128 B per row (BK=64 bf16)
      int su = ((p >> 4) & 7) ^ (row & 7);     // pre-swizzled source slot
      size_t go = (size_t)row * 512 + (size_t)kt * 128 + (size_t)(su << 4);
      int lo = h * 16384 + i * 8192 + w * 1024;  // wave-uniform LDS base
      gl16(Ag + go, bufA + lo);
      gl16(Bg + go, bufB + lo);
    }
  };

  auto ldA = [&](const char* buf, int fm, int kc) -> short8 {
    int row = wr * 128 + fm * 16 + lr;
    int byte = row * 128 + (((kc * 4 + lk) ^ (row & 7)) << 4);
    return *(const short8*)(buf + byte);
  };
  auto ldB = [&](const char* buf, int fn, int kc) -> short8 {
    int row = wc * 64 + fn * 16 + lr;
    int byte = row * 128 + (((kc * 4 + lk) ^ (row & 7)) << 4);
    return *(const short8*)(buf + byte);
  };

  // prologue: stage K-tile 0 completely
  stageHalf(ldsA[0], ldsB[0], 0, 0);
  stageHalf(ldsA[0], ldsB[0], 0, 1);
  asm volatile("s_waitcnt vmcnt(0)" ::: "memory");
  __builtin_amdgcn_sched_barrier(0);
  __builtin_amdgcn_s_barrier();

#pragma unroll
  for (int kt = 0; kt < 4; ++kt) {
    char* curA = ldsA[kt & 1];
    char* curB = ldsB[kt & 1];
    char* nxtA = ldsA[(kt & 1) ^ 1];
    char* nxtB = ldsB[(kt & 1) ^ 1];
    short8 bfr[4][2];
#pragma unroll
    for (int p = 0; p < 4; ++p) {
      if (p == 0) {
#pragma unroll
        for (int fn = 0; fn < 4; ++fn)
#pragma unroll
          for (int kc = 0; kc < 2; ++kc) bfr[fn][kc] = ldB(curB, fn, kc);
      }
      short8 afr[2][2];
#pragma unroll
      for (int i = 0; i < 2; ++i)
#pragma unroll
        for (int kc = 0; kc < 2; ++kc) afr[i][kc] = ldA(curA, 2 * p + i, kc);
      if (kt < 3 && p < 2) stageHalf(nxtA, nxtB, kt + 1, p);
      __builtin_amdgcn_s_barrier();
      asm volatile("s_waitcnt lgkmcnt(0)" ::: "memory");
      __builtin_amdgcn_sched_barrier(0);
      __builtin_amdgcn_s_setprio(1);
#pragma unroll
      for (int kc = 0; kc < 2; ++kc)
#pragma unroll
        for (int i = 0; i < 2; ++i)
#pragma unroll
          for (int n = 0; n < 4; ++n)
            acc[2 * p + i][n] = __builtin_amdgcn_mfma_f32_16x16x32_bf16(
                afr[i][kc], bfr[n][kc], acc[2 * p + i][n], 0, 0, 0);
      __builtin_amdgcn_s_setprio(0);
      __builtin_amdgcn_sched_barrier(0);
      if (p == 3 && kt < 3) {
        // next tile fully staged (issued in phases 0-1, ~3 phases ago)
        asm volatile("s_waitcnt vmcnt(0)" ::: "memory");
        __builtin_amdgcn_sched_barrier(0);
      }
      __builtin_amdgcn_s_barrier();
    }
  }

  // Epilogue: exp(S*logit) masked to col<C, per-row sums.
  // 16x16 C/D layout: col = lane&15, row = (lane>>4)*4 + j.
  float* rsbuf = (float*)&ldsA[0][0];  // [4 wc][256 rows] floats = 4 KB
#pragma unroll
  for (int m = 0; m < 8; ++m) {
    float rsj[4] = {0.f, 0.f, 0.f, 0.f};
#pragma unroll
    for (int n = 0; n < 4; ++n) {
      int col = bc * 256 + wc * 64 + n * 16 + lr;
      bool ok = (col < C_CLS);
#pragma unroll
      for (int j = 0; j < 4; ++j)
        rsj[j] += ok ? __expf(S_SCALE * acc[m][n][j]) : 0.f;
    }
#pragma unroll
    for (int mask = 1; mask <= 8; mask <<= 1)
#pragma unroll
      for (int j = 0; j < 4; ++j) rsj[j] += __shfl_xor(rsj[j], mask, 64);
    if (lr == 0) {
#pragma unroll
      for (int j = 0; j < 4; ++j)
        rsbuf[wc * 256 + wr * 128 + m * 16 + lk * 4 + j] = rsj[j];
    }
  }
  __syncthreads();
  if (t < 256) {
    float s = rsbuf[t] + rsbuf[256 + t] + rsbuf[512 + t] + rsbuf[768 + t];
    partials[(size_t)(br * 256 + t) * PSTRIDE + bc] = s;
  }
}

// ---------------- per-row loss + block partial sums ----------------
__global__ __launch_bounds__(256) void k_loss1(const float* __restrict__ partials,
                                               const float* __restrict__ tgt,
                                               float* __restrict__ bsum) {
  __shared__ float wsum[4];
  int i = blockIdx.x * 256 + threadIdx.x;
  const float* p = partials + (size_t)i * PSTRIDE;
  float s = 0.f;
#pragma unroll
  for (int j = 0; j < NCB; ++j) s += p[j];
  float tl = tgt[i];
  float tcv = fminf(fmaxf(tl, -1.0f + 1e-7f), 1.0f - 1e-7f);
  const float cm = 0.95533648912560601964f;   // cos(0.3)
  const float sm = 0.29552020666133957510f;   // sin(0.3)
  float num = S_SCALE * (tcv * cm - sqrtf(fmaxf(1.0f - tcv * tcv, 0.f)) * sm);
  float sum_excl = s - __expf(S_SCALE * tl);
  float denom = __expf(num) + sum_excl;
  float L = num - __logf(denom);
#pragma unroll
  for (int m = 1; m < 64; m <<= 1) L += __shfl_xor(L, m, 64);
  int l = threadIdx.x & 63, w = threadIdx.x >> 6;
  if (l == 0) wsum[w] = L;
  __syncthreads();
  if (threadIdx.x == 0) bsum[blockIdx.x] = wsum[0] + wsum[1] + wsum[2] + wsum[3];
}

__global__ void k_loss2(const float* __restrict__ bsum, float* __restrict__ out) {
  float s = 0.f;
  for (int i = 0; i < 32; ++i) s += bsum[i];
  out[0] = -s / (float)N_ROWS;
}

// ---------------- launch ----------------
extern "C" void kernel_launch(void* const* d_in, const int* in_sizes, int n_in,
                              void* d_out, int out_size, void* d_ws, size_t ws_size,
                              hipStream_t stream) {
  const float* x = (const float*)d_in[0];
  const float* W = (const float*)d_in[1];
  const int* target = (const int*)d_in[2];
  float* out = (float*)d_out;
  char* ws = (char*)d_ws;

  unsigned short* xnb = (unsigned short*)(ws);              // 8192*256*2   = 4,194,304
  unsigned short* Wb = (unsigned short*)(ws + 4194304);     // 10240*256*2  = 5,242,880
  float* tgt = (float*)(ws + 9437184);                      // 8192*4
  float* partials = (float*)(ws + 9469952);                 // 8192*40*4    = 1,310,720
  float* bsum = (float*)(ws + 10780672);                    // 32*4

  k_normtgt<<<2048, 256, 0, stream>>>(x, W, target, xnb, tgt);
  k_convw<<<1280, 256, 0, stream>>>(W, Wb);
  k_gemm<<<1280, 512, 0, stream>>>(xnb, Wb, partials);
  k_loss1<<<32, 256, 0, stream>>>(partials, tgt, bsum);
  k_loss2<<<1, 1, 0, stream>>>(bsum, out);
}

// Round 5
// 76.705 us; speedup vs baseline: 1.2929x; 1.0690x over previous
//
#include <hip/hip_runtime.h>
#include <hip/hip_bf16.h>
#include <stdint.h>

#define S_SCALE 30.0f
#define N_ROWS 8192
#define D_DIM 256
#define C_CLS 10000
#define C_PAD 10240   /* 40 * 256 */
#define NCB 40

typedef __attribute__((ext_vector_type(8))) short short8;
typedef __attribute__((ext_vector_type(4))) float f32x4;
typedef __attribute__((ext_vector_type(4))) unsigned short us4;

static __device__ __forceinline__ unsigned short f2bf(float f) {
  union { float f; unsigned u; } a; a.f = f;
  unsigned r = a.u + 0x7fffu + ((a.u >> 16) & 1u);
  return (unsigned short)(r >> 16);
}

static __device__ __forceinline__ void gl16(const void* g, void* l) {
  __builtin_amdgcn_global_load_lds(
      (const __attribute__((address_space(1))) void*)g,
      (__attribute__((address_space(3))) void*)l, 16, 0, 0);
}

// ------- fused: row L2-normalize -> bf16, exact fp32 target logit -------
__global__ __launch_bounds__(256) void k_normtgt(const float* __restrict__ x,
                                                 const float* __restrict__ W,
                                                 const int* __restrict__ target,
                                                 unsigned short* __restrict__ xnb,
                                                 float* __restrict__ tgt) {
  int row = blockIdx.x * 4 + (threadIdx.x >> 6);
  int l = threadIdx.x & 63;
  const float4 v = *(const float4*)(x + (size_t)row * D_DIM + l * 4);
  float ss = v.x * v.x + v.y * v.y + v.z * v.z + v.w * v.w;
#pragma unroll
  for (int m = 1; m < 64; m <<= 1) ss += __shfl_xor(ss, m, 64);
  float rn = 1.0f / sqrtf(ss);
  us4 o;
  o.x = f2bf(v.x * rn); o.y = f2bf(v.y * rn);
  o.z = f2bf(v.z * rn); o.w = f2bf(v.w * rn);
  *(us4*)(xnb + (size_t)row * D_DIM + l * 4) = o;
  int tc = target[row];
  const float4 b = *(const float4*)(W + (size_t)tc * D_DIM + l * 4);
  float s = v.x * b.x + v.y * b.y + v.z * b.z + v.w * b.w;
#pragma unroll
  for (int m = 1; m < 64; m <<= 1) s += __shfl_xor(s, m, 64);
  if (l == 0) tgt[row] = s * rn;
}

// ---------------- W fp32 -> bf16, zero-pad rows to C_PAD ----------------
__global__ __launch_bounds__(256) void k_convw(const float* __restrict__ W,
                                               unsigned short* __restrict__ Wb) {
  int idx = blockIdx.x * 256 + threadIdx.x;   // 8 elems per thread
  size_t base = (size_t)idx * 8;
  int row = (int)(base >> 8);
  us4 o0 = {0, 0, 0, 0}, o1 = {0, 0, 0, 0};
  if (row < C_CLS) {
    const float4 a = *(const float4*)(W + base);
    const float4 b = *(const float4*)(W + base + 4);
    o0.x = f2bf(a.x); o0.y = f2bf(a.y); o0.z = f2bf(a.z); o0.w = f2bf(a.w);
    o1.x = f2bf(b.x); o1.y = f2bf(b.y); o1.z = f2bf(b.z); o1.w = f2bf(b.w);
  }
  *(us4*)(Wb + base) = o0;
  *(us4*)(Wb + base + 4) = o1;
}

// ------- persistent fused bf16 GEMM (256x256, 8-phase) + exp-sum epilogue -------
// 256 blocks (1/CU), each owns fixed br and loops 5 consecutive bc tiles ->
// one continuous 20-K-step pipeline (1 prologue, epilogues overlap staging).
// BK=64, 8 waves (2Mx4N), wave tile 128x64 = 8x4 frags of 16x16x32.
// T2 swizzle: LDS slot ^= row&7 (pre-swizzled global source, linear gl16 dest).
// T1: per-XCD 16 br x 10 bc chunk = 3.25 MB working set (L2-fit).
__global__ __launch_bounds__(512, 2) void k_gemm(const unsigned short* __restrict__ xnb,
                                                 const unsigned short* __restrict__ Wb,
                                                 float* __restrict__ partials) {
  __shared__ __align__(16) char lds[135168];
  // layout: A0 @0, A1 @32768, B0 @65536, B1 @98304, rowsum @131072 (4 KB)
  const int b = blockIdx.x;
  const int x8 = b & 7, q = b >> 3;
  const int br = (x8 >> 2) * 16 + (q & 15);           // fixed per block
  const int bc0 = (x8 & 3) * 10 + (q >> 4) * 5;       // first of 5 tiles
  const int t = threadIdx.x;
  const int w = t >> 6, l = t & 63;
  const int wr = w >> 2, wc = w & 3;                  // 2M x 4N waves
  const int lr = l & 15, lk = l >> 4;
  const char* Ag = (const char*)xnb + (size_t)br * 256 * 512;  // 512 B/row
  const char* BgT = (const char*)Wb + (size_t)bc0 * 256 * 512;

  f32x4 acc[8][4];
#pragma unroll
  for (int m = 0; m < 8; m++)
#pragma unroll
    for (int n = 0; n < 4; n++) acc[m][n] = (f32x4){0.f, 0.f, 0.f, 0.f};

  auto stageHalf = [&](char* bufA, char* bufB, const char* BgS, int kt, int h) {
#pragma unroll
    for (int i = 0; i < 2; ++i) {
      int p = h * 16384 + i * 8192 + t * 16;   // linear dest byte
      int row = p >> 7;                        // 128 B per row (BK=64 bf16)
      int su = ((p >> 4) & 7) ^ (row & 7);     // pre-swizzled source slot
      size_t go = (size_t)row * 512 + (size_t)(kt * 128) + (size_t)(su << 4);
      int lo = h * 16384 + i * 8192 + w * 1024;  // wave-uniform LDS base
      gl16(Ag + go, bufA + lo);
      gl16(BgS + go, bufB + lo);
    }
  };

  auto ldA = [&](const char* buf, int fm, int kc) -> short8 {
    int row = wr * 128 + fm * 16 + lr;
    int byte = row * 128 + (((kc * 4 + lk) ^ (row & 7)) << 4);
    return *(const short8*)(buf + byte);
  };
  auto ldB = [&](const char* buf, int fn, int kc) -> short8 {
    int row = wc * 64 + fn * 16 + lr;
    int byte = row * 128 + (((kc * 4 + lk) ^ (row & 7)) << 4);
    return *(const short8*)(buf + byte);
  };

  // prologue: stage tile0 K-tile0 into buf0
  stageHalf(lds + 0, lds + 65536, BgT, 0, 0);
  stageHalf(lds + 0, lds + 65536, BgT, 0, 1);
  asm volatile("s_waitcnt vmcnt(0)" ::: "memory");
  __builtin_amdgcn_sched_barrier(0);
  __builtin_amdgcn_s_barrier();

  char* cA = lds + 0;     char* cB = lds + 65536;
  char* nA = lds + 32768; char* nB = lds + 98304;
  float* rsum = (float*)(lds + 131072);

  for (int tt = 0; tt < 5; ++tt) {
    const char* BgN = BgT + 131072;  // next tile's B panel (bc+1)
    for (int kt = 0; kt < 4; ++kt) {
      const char* BgS = (kt < 3) ? BgT : BgN;
      int ktn = (kt + 1) & 3;
      bool doStage = !(tt == 4 && kt == 3);
      short8 bfr[4][2];
#pragma unroll
      for (int p = 0; p < 4; ++p) {
        if (p == 0) {
#pragma unroll
          for (int fn = 0; fn < 4; ++fn)
#pragma unroll
            for (int kc = 0; kc < 2; ++kc) bfr[fn][kc] = ldB(cB, fn, kc);
        }
        short8 afr[2][2];
#pragma unroll
        for (int i = 0; i < 2; ++i)
#pragma unroll
          for (int kc = 0; kc < 2; ++kc) afr[i][kc] = ldA(cA, 2 * p + i, kc);
        if (p < 2 && doStage) stageHalf(nA, nB, BgS, ktn, p);
        __builtin_amdgcn_s_barrier();
        asm volatile("s_waitcnt lgkmcnt(0)" ::: "memory");
        __builtin_amdgcn_sched_barrier(0);
        __builtin_amdgcn_s_setprio(1);
#pragma unroll
        for (int kc = 0; kc < 2; ++kc)
#pragma unroll
          for (int i = 0; i < 2; ++i)
#pragma unroll
            for (int n = 0; n < 4; ++n)
              acc[2 * p + i][n] = __builtin_amdgcn_mfma_f32_16x16x32_bf16(
                  afr[i][kc], bfr[n][kc], acc[2 * p + i][n], 0, 0, 0);
        __builtin_amdgcn_s_setprio(0);
        __builtin_amdgcn_sched_barrier(0);
        if (p == 3) {
          asm volatile("s_waitcnt vmcnt(0)" ::: "memory");
          __builtin_amdgcn_sched_barrier(0);
        }
        __builtin_amdgcn_s_barrier();
      }
      { char* s0 = cA; cA = nA; nA = s0; }
      { char* s1 = cB; cB = nB; nB = s1; }
    }

    // Epilogue tile tt: exp(S*logit) masked to col<C, per-row sums, zero acc.
    // 16x16 C/D layout: col = lane&15, row = (lane>>4)*4 + j.
    int bc = bc0 + tt;
#pragma unroll
    for (int m = 0; m < 8; ++m) {
      float rsj[4] = {0.f, 0.f, 0.f, 0.f};
#pragma unroll
      for (int n = 0; n < 4; ++n) {
        int col = bc * 256 + wc * 64 + n * 16 + lr;
        bool ok = (col < C_CLS);
#pragma unroll
        for (int j = 0; j < 4; ++j)
          rsj[j] += ok ? __expf(S_SCALE * acc[m][n][j]) : 0.f;
        acc[m][n] = (f32x4){0.f, 0.f, 0.f, 0.f};
      }
#pragma unroll
      for (int mask = 1; mask <= 8; mask <<= 1)
#pragma unroll
        for (int j = 0; j < 4; ++j) rsj[j] += __shfl_xor(rsj[j], mask, 64);
      if (lr == 0) {
#pragma unroll
        for (int j = 0; j < 4; ++j)
          rsum[wc * 256 + wr * 128 + m * 16 + lk * 4 + j] = rsj[j];
      }
    }
    __syncthreads();
    if (t < 256) {
      float sv = rsum[t] + rsum[256 + t] + rsum[512 + t] + rsum[768 + t];
      partials[(size_t)bc * N_ROWS + (size_t)br * 256 + t] = sv;  // coalesced
    }
    BgT = BgN;
  }
}

// ---------------- per-row loss + block partial sums ----------------
__global__ __launch_bounds__(256) void k_loss1(const float* __restrict__ partials,
                                               const float* __restrict__ tgt,
                                               float* __restrict__ bsum) {
  __shared__ float wsum[4];
  int i = blockIdx.x * 256 + threadIdx.x;
  const float* p = partials + i;
  float s = 0.f;
#pragma unroll
  for (int j = 0; j < NCB; ++j) s += p[(size_t)j * N_ROWS];
  float tl = tgt[i];
  float tcv = fminf(fmaxf(tl, -1.0f + 1e-7f), 1.0f - 1e-7f);
  const float cm = 0.95533648912560601964f;   // cos(0.3)
  const float sm = 0.29552020666133957510f;   // sin(0.3)
  float num = S_SCALE * (tcv * cm - sqrtf(fmaxf(1.0f - tcv * tcv, 0.f)) * sm);
  float sum_excl = s - __expf(S_SCALE * tl);
  float denom = __expf(num) + sum_excl;
  float L = num - __logf(denom);
#pragma unroll
  for (int m = 1; m < 64; m <<= 1) L += __shfl_xor(L, m, 64);
  int l = threadIdx.x & 63, w = threadIdx.x >> 6;
  if (l == 0) wsum[w] = L;
  __syncthreads();
  if (threadIdx.x == 0) bsum[blockIdx.x] = wsum[0] + wsum[1] + wsum[2] + wsum[3];
}

__global__ void k_loss2(const float* __restrict__ bsum, float* __restrict__ out) {
  float s = 0.f;
  for (int i = 0; i < 32; ++i) s += bsum[i];
  out[0] = -s / (float)N_ROWS;
}

// ---------------- launch ----------------
extern "C" void kernel_launch(void* const* d_in, const int* in_sizes, int n_in,
                              void* d_out, int out_size, void* d_ws, size_t ws_size,
                              hipStream_t stream) {
  const float* x = (const float*)d_in[0];
  const float* W = (const float*)d_in[1];
  const int* target = (const int*)d_in[2];
  float* out = (float*)d_out;
  char* ws = (char*)d_ws;

  unsigned short* xnb = (unsigned short*)(ws);              // 8192*256*2   = 4,194,304
  unsigned short* Wb = (unsigned short*)(ws + 4194304);     // 10240*256*2  = 5,242,880
  float* tgt = (float*)(ws + 9437184);                      // 8192*4
  float* partials = (float*)(ws + 9469952);                 // 40*8192*4    = 1,310,720
  float* bsum = (float*)(ws + 10780672);                    // 32*4

  k_normtgt<<<2048, 256, 0, stream>>>(x, W, target, xnb, tgt);
  k_convw<<<1280, 256, 0, stream>>>(W, Wb);
  k_gemm<<<256, 512, 0, stream>>>(xnb, Wb, partials);
  k_loss1<<<32, 256, 0, stream>>>(partials, tgt, bsum);
  k_loss2<<<1, 1, 0, stream>>>(bsum, out);
}